// Round 4
// baseline (8004.968 us; speedup 1.0000x reference)
//
#include <hip/hip_runtime.h>
#include <hip/hip_bf16.h>
#include <cstdint>

#define NB 16
#define NC 32
#define T0 16384
#define NL 30
#define SKC 256
#define TF 13315
#define TCH 1920          // time-chunk size (final coords), multiple of 64
#define XPB 4992          // ping-pong row capacity (Tc + 3068, padded)

typedef _Float16 f16;
typedef _Float16 f16x2 __attribute__((ext_vector_type(2)));
typedef _Float16 f16x8 __attribute__((ext_vector_type(8)));
typedef float f32x4 __attribute__((ext_vector_type(4)));

#define MFMA16(a,b,c) __builtin_amdgcn_mfma_f32_16x16x32_f16(a,b,c,0,0,0)

__device__ __forceinline__ float fdot2c(uint32_t w, uint32_t x, float c){
#if __has_builtin(__builtin_amdgcn_fdot2)
  return __builtin_amdgcn_fdot2(__builtin_bit_cast(f16x2, w),
                                __builtin_bit_cast(f16x2, x), c, false);
#else
  f16x2 a = __builtin_bit_cast(f16x2, w), b = __builtin_bit_cast(f16x2, x);
  return c + (float)a.x*(float)b.x + (float)a.y*(float)b.y;
#endif
}

// ---------------- prep: weights -> f16 fragment order / dot2 pairs ----------
__global__ __launch_bounds__(256) void prep2(
    const float* __restrict__ sw, const float* __restrict__ e1w,
    const float* __restrict__ e2w, const float* __restrict__ fw,
    const float* __restrict__ gw, const float* __restrict__ rw,
    f16* __restrict__ wsk, f16* __restrict__ e1f, f16* __restrict__ e2f,
    uint32_t* __restrict__ fgp, uint32_t* __restrict__ ggp,
    uint32_t* __restrict__ rwp){
  int idx = blockIdx.x*256 + threadIdx.x;
  if (idx < 30720){                    // skip weights frag: [i][mt][lane][8]
    int lane = idx & 63, mt = (idx>>6)&15, i = idx>>10;
    int m = mt*16 + (lane&15);
    int kl = (lane>>4)*8;
    const float* s = sw + ((size_t)i*SKC + m)*NC + kl;
    f16* dp = wsk + (size_t)idx*8;
    #pragma unroll
    for (int j=0;j<8;j++) dp[j] = (f16)s[j];
  } else if (idx < 38912){             // e1 frag: [ks][mt][lane][8]
    int j2 = idx - 30720;
    int lane = j2&63, mt = (j2>>6)&15, ks = j2>>10;
    int m = mt*16 + (lane&15);
    int k = ks*32 + (lane>>4)*8;
    const float* s = e1w + (size_t)m*SKC + k;
    f16* dp = e1f + (size_t)j2*8;
    #pragma unroll
    for (int j=0;j<8;j++) dp[j] = (f16)s[j];
  } else if (idx < 47104){             // e2 frag
    int j2 = idx - 38912;
    int lane = j2&63, mt = (j2>>6)&15, ks = j2>>10;
    int m = mt*16 + (lane&15);
    int k = ks*32 + (lane>>4)*8;
    const float* s = e2w + (size_t)m*SKC + k;
    f16* dp = e2f + (size_t)j2*8;
    #pragma unroll
    for (int j=0;j<8;j++) dp[j] = (f16)s[j];
  } else if (idx < 77824){             // filt pairs: [i][co][ci] (2 taps)
    int j2 = idx - 47104;
    const float* s = fw + (size_t)j2*2;
    f16x2 p; p.x = (f16)s[0]; p.y = (f16)s[1];
    fgp[j2] = __builtin_bit_cast(uint32_t, p);
  } else if (idx < 108544){            // gate pairs
    int j2 = idx - 77824;
    const float* s = gw + (size_t)j2*2;
    f16x2 p; p.x = (f16)s[0]; p.y = (f16)s[1];
    ggp[j2] = __builtin_bit_cast(uint32_t, p);
  } else if (idx < 123904){            // res pairs
    int j2 = idx - 108544;
    int i = j2 >> 9, c = (j2>>4)&31, j = j2&15;
    const float* s = rw + ((size_t)i*NC + c)*NC + 2*j;
    f16x2 p; p.x = (f16)s[0]; p.y = (f16)s[1];
    rwp[j2] = __builtin_bit_cast(uint32_t, p);
  }
}

// ---------------- causal: y[16,1,T] -> x0[b][t][32] f16 ----------------
__global__ __launch_bounds__(256) void causal2(
    const float* __restrict__ y, const float* __restrict__ cw,
    const float* __restrict__ cb, f16* __restrict__ x0){
  int idx = blockIdx.x*256 + threadIdx.x;
  int b = idx >> 14, t = idx & (T0-1);
  float yv = y[idx];
  uint32_t wpk[16];
  #pragma unroll
  for (int j=0;j<16;j++){
    f16x2 p;
    p.x = (f16)(cw[2*j]*yv + cb[2*j]);
    p.y = (f16)(cw[2*j+1]*yv + cb[2*j+1]);
    wpk[j] = __builtin_bit_cast(uint32_t, p);
  }
  uint4* dst = (uint4*)(x0 + ((size_t)b*T0 + t)*NC);
  dst[0] = make_uint4(wpk[0],wpk[1],wpk[2],wpk[3]);
  dst[1] = make_uint4(wpk[4],wpk[5],wpk[6],wpk[7]);
  dst[2] = make_uint4(wpk[8],wpk[9],wpk[10],wpk[11]);
  dst[3] = make_uint4(wpk[12],wpk[13],wpk[14],wpk[15]);
}

// ---------------- shared per-column layer math ----------------
__device__ __forceinline__ void layer_core(
    const uint4* A4p, const uint4* B4p,
    const uint32_t* __restrict__ fp0, const uint32_t* __restrict__ gp0,
    const uint32_t* __restrict__ rp0,
    uint32_t* zp, uint32_t* xo){
  uint4 A4[4], B4[4];
  #pragma unroll
  for (int q=0;q<4;q++){ A4[q] = A4p[q]; B4[q] = B4p[q]; }
  uint32_t Aw[16], Bw[16];
  #pragma unroll
  for (int q=0;q<4;q++){
    Aw[4*q+0]=A4[q].x; Aw[4*q+1]=A4[q].y; Aw[4*q+2]=A4[q].z; Aw[4*q+3]=A4[q].w;
    Bw[4*q+0]=B4[q].x; Bw[4*q+1]=B4[q].y; Bw[4*q+2]=B4[q].z; Bw[4*q+3]=B4[q].w;
  }
  uint32_t xp[32]; float x1f[32];
  #pragma unroll
  for (int wd=0; wd<16; wd++){
    uint32_t a = Aw[wd], bb = Bw[wd];
    xp[2*wd]   = (a & 0xffffu) | (bb << 16);
    xp[2*wd+1] = (a >> 16) | (bb & 0xffff0000u);
    f16x2 bh = __builtin_bit_cast(f16x2, bb);
    x1f[2*wd] = (float)bh.x; x1f[2*wd+1] = (float)bh.y;
  }
  float z[32];
  for (int co=0; co<32; co++){
    const uint32_t* fp = fp0 + co*32;
    const uint32_t* gp = gp0 + co*32;
    float f = 0.f, g = 0.f;
    #pragma unroll
    for (int ci=0; ci<32; ci++){
      f = fdot2c(fp[ci], xp[ci], f);
      g = fdot2c(gp[ci], xp[ci], g);
    }
    f = fminf(fmaxf(f, -30.f), 30.f);
    g = fminf(fmaxf(g, -30.f), 30.f);
    float ef = __expf(-2.f*f);
    z[co] = ((1.f - ef)/(1.f + ef)) * (1.f/(1.f + __expf(-g)));
  }
  #pragma unroll
  for (int j=0;j<16;j++){
    f16x2 p; p.x = (f16)z[2*j]; p.y = (f16)z[2*j+1];
    zp[j] = __builtin_bit_cast(uint32_t, p);
  }
  #pragma unroll
  for (int j=0;j<16;j++){
    float a0 = x1f[2*j], a1 = x1f[2*j+1];
    const uint32_t* r0 = rp0 + (2*j)*16;
    const uint32_t* r1 = rp0 + (2*j+1)*16;
    #pragma unroll
    for (int k=0;k<16;k++){
      a0 = fdot2c(r0[k], zp[k], a0);
      a1 = fdot2c(r1[k], zp[k], a1);
    }
    f16x2 p; p.x = (f16)a0; p.y = (f16)a1;
    xo[j] = __builtin_bit_cast(uint32_t, p);
  }
}

// ---------------- single dilated layer (d=128/256/512) ----------------
__global__ __launch_bounds__(256) void layer_single(
    const f16* __restrict__ xin, f16* __restrict__ xout, f16* __restrict__ zl,
    const uint32_t* __restrict__ fp0, const uint32_t* __restrict__ gp0,
    const uint32_t* __restrict__ rp0,
    int inB, int inOff, int outB, int Tout, int d, int trim, int Tcp){
  int t = blockIdx.x*256 + threadIdx.x;
  int b = blockIdx.y;
  if (t >= Tout) return;
  const uint4* xa = (const uint4*)(xin + ((size_t)b*inB + inOff + t)*NC);
  const uint4* xb = (const uint4*)(xin + ((size_t)b*inB + inOff + t + d)*NC);
  uint32_t zp[16], xo[16];
  layer_core(xa, xb, fp0, gp0, rp0, zp, xo);
  if (t >= trim){
    uint4* zo = (uint4*)(zl + ((size_t)b*Tcp + (t - trim))*NC);
    zo[0] = make_uint4(zp[0],zp[1],zp[2],zp[3]);
    zo[1] = make_uint4(zp[4],zp[5],zp[6],zp[7]);
    zo[2] = make_uint4(zp[8],zp[9],zp[10],zp[11]);
    zo[3] = make_uint4(zp[12],zp[13],zp[14],zp[15]);
  }
  uint4* xod = (uint4*)(xout + ((size_t)b*outB + t)*NC);
  xod[0] = make_uint4(xo[0],xo[1],xo[2],xo[3]);
  xod[1] = make_uint4(xo[4],xo[5],xo[6],xo[7]);
  xod[2] = make_uint4(xo[8],xo[9],xo[10],xo[11]);
  xod[3] = make_uint4(xo[12],xo[13],xo[14],xo[15]);
}

// ---------------- fused 7-layer group (d = 1..64), LDS-resident x -----------
struct Trim7 { int t[7]; };

__global__ __launch_bounds__(256) void group7(
    const f16* __restrict__ xin, int inB, int inOff,
    f16* __restrict__ xout, int outB,
    f16* __restrict__ zbase, size_t zls, int g0,
    int Lfinal, int TcAct, int Tcp,
    const uint32_t* __restrict__ fgp, const uint32_t* __restrict__ ggp,
    const uint32_t* __restrict__ rwp, Trim7 trims){
  __shared__ uint4 xb[2][384*5];   // [384 pos][stride 5 uint4 = 80B], 61.4 KB
  int tid = threadIdx.x, b = blockIdx.y, o0 = blockIdx.x*256;
  int Cf = Lfinal - o0; if (Cf > 256) Cf = 256;
  int Cin = Cf + 127;
  for (int p = tid; p < Cin; p += 256){
    const uint4* src = (const uint4*)(xin + ((size_t)b*inB + inOff + o0 + p)*NC);
    uint4* dst = &xb[0][p*5];
    dst[0]=src[0]; dst[1]=src[1]; dst[2]=src[2]; dst[3]=src[3];
  }
  __syncthreads();
  int cur = 0;
  for (int li = 0; li < 7; li++){
    int d = 1 << li;
    int count = Cf + 128 - (2 << li);
    const uint32_t* fp0 = fgp + (size_t)(g0+li)*1024;
    const uint32_t* gp0 = ggp + (size_t)(g0+li)*1024;
    const uint32_t* rp0 = rwp + (size_t)(g0+li)*512;
    f16* zl = zbase + (size_t)(g0+li)*zls + (size_t)b*Tcp*NC;
    int trim = trims.t[li];
    for (int p = tid; p < count; p += 256){
      uint32_t zp[16], xo[16];
      layer_core(&xb[cur][p*5], &xb[cur][(p+d)*5], fp0, gp0, rp0, zp, xo);
      int lz = o0 + p - trim;
      if (lz >= 0 && lz < TcAct){
        uint4* zo = (uint4*)(zl + (size_t)lz*NC);
        zo[0] = make_uint4(zp[0],zp[1],zp[2],zp[3]);
        zo[1] = make_uint4(zp[4],zp[5],zp[6],zp[7]);
        zo[2] = make_uint4(zp[8],zp[9],zp[10],zp[11]);
        zo[3] = make_uint4(zp[12],zp[13],zp[14],zp[15]);
      }
      uint4* D = &xb[cur^1][p*5];
      D[0] = make_uint4(xo[0],xo[1],xo[2],xo[3]);
      D[1] = make_uint4(xo[4],xo[5],xo[6],xo[7]);
      D[2] = make_uint4(xo[8],xo[9],xo[10],xo[11]);
      D[3] = make_uint4(xo[12],xo[13],xo[14],xo[15]);
    }
    __syncthreads();
    cur ^= 1;
  }
  if (tid < Cf){
    uint4* dst = (uint4*)(xout + ((size_t)b*outB + o0 + tid)*NC);
    const uint4* src = &xb[cur][tid*5];
    dst[0]=src[0]; dst[1]=src[1]; dst[2]=src[2]; dst[3]=src[3];
  }
}

// ------- fused skip(K=960) -> relu -> end1 -> relu -> end2, write f32 -------
__global__ __launch_bounds__(256) void skipend(
    const f16* __restrict__ zbase, size_t zls,
    const f16* __restrict__ wsk, const f16* __restrict__ e1f,
    const float* __restrict__ e1b, const f16* __restrict__ e2f,
    const float* __restrict__ e2b, float* __restrict__ out,
    int tc0, int TcAct, int Tcp){
  __shared__ uint4 smem4[4224];               // 67,584 B
  f16* Ab = (f16*)smem4;                      // phase1: [2][8192]
  f16* Zb = (f16*)smem4 + 32768/2;            // phase1: [2][2048]
  f16* sA = (f16*)smem4;                      // phase2+: [64][264]
  f16* sB = (f16*)smem4 + 33792/2;
  int tid = threadIdx.x, b = blockIdx.y, t0 = blockIdx.x*64;
  int w = tid>>6, lane = tid&63;
  int tl = w*16 + (lane&15);
  int kq = (lane>>4)*8;
  int rq = (lane>>4)*4;

  // staging helpers (reg round-trip; issue loads early, store late)
  const uint4* wsk4 = (const uint4*)wsk;
  uint4 st[5];
  auto stLoad = [&](int l){
    const uint4* s = wsk4 + (size_t)l*1024 + tid*4;
    st[0]=s[0]; st[1]=s[1]; st[2]=s[2]; st[3]=s[3];
    int t = tid>>2, c8 = tid&3;
    st[4] = *(const uint4*)(zbase + (size_t)l*zls + ((size_t)b*Tcp + t0 + t)*NC + c8*8);
  };
  auto stStore = [&](int l){
    int buf = l & 1;
    uint4* d = (uint4*)(Ab + buf*8192) + tid*4;
    d[0]=st[0]; d[1]=st[1]; d[2]=st[2]; d[3]=st[3];
    *((uint4*)(Zb + buf*2048) + tid) = st[4];
  };

  f32x4 acc[16];
  #pragma unroll
  for (int mt=0; mt<16; mt++) acc[mt] = f32x4{0.f,0.f,0.f,0.f};

  stLoad(0); stStore(0);
  for (int l = 0; l < NL; l++){
    __syncthreads();
    if (l+1 < NL) stLoad(l+1);               // issue early
    int buf = l & 1;
    f16x8 bf = *(const f16x8*)(Zb + buf*2048 + (size_t)(tl*32 + kq));
    const f16x8* ap = (const f16x8*)(Ab + buf*8192) + lane;
    #pragma unroll
    for (int mt=0; mt<16; mt++)
      acc[mt] = MFMA16(ap[mt*64], bf, acc[mt]);
    if (l+1 < NL) stStore(l+1);              // write late (hidden under MFMA)
  }
  __syncthreads();
  // phase2: relu(skip) -> sA [t][c]
  #pragma unroll
  for (int mt=0; mt<16; mt++)
    #pragma unroll
    for (int r=0;r<4;r++)
      sA[(size_t)tl*264 + mt*16 + rq + r] = (f16)fmaxf(acc[mt][r], 0.f);
  __syncthreads();
  // phase3: end1
  f32x4 a2[16];
  #pragma unroll
  for (int mt=0; mt<16; mt++) a2[mt] = f32x4{0.f,0.f,0.f,0.f};
  #pragma unroll
  for (int ks=0; ks<8; ks++){
    f16x8 bf = *(const f16x8*)&sA[(size_t)tl*264 + ks*32 + kq];
    const f16x8* wp = (const f16x8*)e1f + (size_t)(ks*16)*64 + lane;
    #pragma unroll
    for (int mt=0; mt<16; mt++)
      a2[mt] = MFMA16(wp[mt*64], bf, a2[mt]);
  }
  #pragma unroll
  for (int mt=0; mt<16; mt++){
    #pragma unroll
    for (int r=0;r<4;r++){
      int c = mt*16 + rq + r;
      sB[(size_t)tl*264 + c] = (f16)fmaxf(a2[mt][r] + e1b[c], 0.f);
    }
  }
  __syncthreads();
  // phase4: end2 + final write
  #pragma unroll
  for (int mt=0; mt<16; mt++) a2[mt] = f32x4{0.f,0.f,0.f,0.f};
  #pragma unroll
  for (int ks=0; ks<8; ks++){
    f16x8 bf = *(const f16x8*)&sB[(size_t)tl*264 + ks*32 + kq];
    const f16x8* wp = (const f16x8*)e2f + (size_t)(ks*16)*64 + lane;
    #pragma unroll
    for (int mt=0; mt<16; mt++)
      a2[mt] = MFMA16(wp[mt*64], bf, a2[mt]);
  }
  int tt = t0 + tl;
  if (tt < TcAct){
    #pragma unroll
    for (int mt=0; mt<16; mt++){
      #pragma unroll
      for (int r=0;r<4;r++){
        int c = mt*16 + rq + r;
        out[((size_t)b*SKC + c)*TF + tc0 + tt] = a2[mt][r] + e2b[c];
      }
    }
  }
}

extern "C" void kernel_launch(void* const* d_in, const int* in_sizes, int n_in,
                              void* d_out, int out_size, void* d_ws, size_t ws_size,
                              hipStream_t stream) {
  (void)in_sizes; (void)n_in; (void)out_size; (void)ws_size;
  const float* y   = (const float*)d_in[0];
  const float* cw  = (const float*)d_in[1];
  const float* cb  = (const float*)d_in[2];
  const float* fw  = (const float*)d_in[3];
  const float* gw  = (const float*)d_in[4];
  const float* rw  = (const float*)d_in[5];
  const float* sw  = (const float*)d_in[6];
  const float* e1w = (const float*)d_in[7];
  const float* e1b = (const float*)d_in[8];
  const float* e2w = (const float*)d_in[9];
  const float* e2b = (const float*)d_in[10];
  float* out = (float*)d_out;
  char* ws = (char*)d_ws;

  // ws layout (total 87,044,096 B <= proven ws >= 89.4 MB)
  f16* x0full = (f16*)(ws);                       // 16,777,216
  f16* xpA    = (f16*)(ws + 16777216);            //  5,111,808
  f16* xpB    = (f16*)(ws + 21889024);            //  5,111,808
  f16* wsk    = (f16*)(ws + 27000832);            //    491,520
  f16* e1f    = (f16*)(ws + 27492352);            //    131,072
  f16* e2f    = (f16*)(ws + 27623424);            //    131,072
  uint32_t* fgp = (uint32_t*)(ws + 27754496);     //    122,880
  uint32_t* ggp = (uint32_t*)(ws + 27877376);     //    122,880
  uint32_t* rwp = (uint32_t*)(ws + 28000256);     //     61,440
  f16* zstack = (f16*)(ws + 28061696);            // 58,982,400
  const size_t zls = (size_t)NB*TCH*NC;           // f16 per z layer

  // suffix dilation sums S[i] = sum_{j>=i} d_j
  int S[NL+1]; S[NL] = 0;
  for (int i = NL-1; i >= 0; i--) S[i] = S[i+1] + (1 << (i % 10));

  prep2<<<dim3(484), 256, 0, stream>>>(sw, e1w, e2w, fw, gw, rw,
                                       wsk, e1f, e2f, fgp, ggp, rwp);
  causal2<<<dim3(1024), 256, 0, stream>>>(y, cw, cb, x0full);

  f16* pp[2] = {xpA, xpB};
  for (int tc0 = 0; tc0 < TF; tc0 += TCH){
    int TcAct = TF - tc0; if (TcAct > TCH) TcAct = TCH;
    int cur = -1;  // -1 means x0full
    for (int s = 0; s < 3; s++){
      int g0 = s*10;
      // group layers g0..g0+6 (d=1..64)
      Trim7 tr;
      for (int li = 0; li < 7; li++) tr.t[li] = S[g0+li+1];
      int Lfinal = TcAct + S[g0+7];
      const f16* gin = (cur < 0) ? x0full : pp[cur];
      int inB  = (cur < 0) ? T0 : XPB;
      int inOff = (cur < 0) ? tc0 : 0;
      int nxt = (cur < 0) ? 0 : (cur^1);
      group7<<<dim3((Lfinal + 255)/256, NB), 256, 0, stream>>>(
          gin, inB, inOff, pp[nxt], XPB, zstack, zls, g0,
          Lfinal, TcAct, TCH, fgp, ggp, rwp, tr);
      cur = nxt;
      // singles g0+7..g0+9 (d=128,256,512)
      for (int i = g0+7; i <= g0+9; i++){
        int d = 1 << (i % 10);
        int Tout = TcAct + S[i+1];
        layer_single<<<dim3((Tout + 255)/256, NB), 256, 0, stream>>>(
            pp[cur], pp[cur^1], zstack + (size_t)i*zls,
            fgp + (size_t)i*1024, ggp + (size_t)i*1024, rwp + (size_t)i*512,
            XPB, 0, XPB, Tout, d, S[i+1], TCH);
        cur ^= 1;
      }
    }
    skipend<<<dim3((TcAct + 63)/64, NB), 256, 0, stream>>>(
        zstack, zls, wsk, e1f, e1b, e2f, e2b, out, tc0, TcAct, TCH);
  }
}

// Round 5
// 7154.172 us; speedup vs baseline: 1.1189x; 1.1189x over previous
//
#include <hip/hip_runtime.h>
#include <hip/hip_bf16.h>
#include <cstdint>

#define NB 16
#define NC 32
#define T0 16384
#define NL 30
#define SKC 256
#define TF 13315
#define TC 2432           // time-chunk (final coords); 38*64
#define XPB 5376          // ping-pong row capacity (>= TC + 2942)
#define ZLS ((size_t)NB*TC*NC)   // f16 elements per z layer

typedef _Float16 f16;
typedef _Float16 f16x2 __attribute__((ext_vector_type(2)));
typedef _Float16 f16x8 __attribute__((ext_vector_type(8)));
typedef float f32x4 __attribute__((ext_vector_type(4)));

#define MFMA16(a,b,c) __builtin_amdgcn_mfma_f32_16x16x32_f16(a,b,c,0,0,0)

__device__ __forceinline__ float fdot2c(uint32_t w, uint32_t x, float c){
#if __has_builtin(__builtin_amdgcn_fdot2)
  return __builtin_amdgcn_fdot2(__builtin_bit_cast(f16x2, w),
                                __builtin_bit_cast(f16x2, x), c, false);
#else
  f16x2 a = __builtin_bit_cast(f16x2, w), b = __builtin_bit_cast(f16x2, x);
  return c + (float)a.x*(float)b.x + (float)a.y*(float)b.y;
#endif
}

__device__ __forceinline__ float frcp(float x){
#if __has_builtin(__builtin_amdgcn_rcpf)
  return __builtin_amdgcn_rcpf(x);
#else
  return 1.f/x;
#endif
}

// ---------------- prep: weights -> f16 fragment order / dot2 pairs ----------
__global__ __launch_bounds__(256) void prep2(
    const float* __restrict__ sw, const float* __restrict__ e1w,
    const float* __restrict__ e2w, const float* __restrict__ fw,
    const float* __restrict__ gw, const float* __restrict__ rw,
    f16* __restrict__ wsk, f16* __restrict__ e1f, f16* __restrict__ e2f,
    uint32_t* __restrict__ fgp, uint32_t* __restrict__ ggp,
    uint32_t* __restrict__ rwp){
  int idx = blockIdx.x*256 + threadIdx.x;
  if (idx < 30720){                    // skip weights frag: [i][mt][lane][8]
    int lane = idx & 63, mt = (idx>>6)&15, i = idx>>10;
    int m = mt*16 + (lane&15);
    int kl = (lane>>4)*8;
    const float* s = sw + ((size_t)i*SKC + m)*NC + kl;
    f16* dp = wsk + (size_t)idx*8;
    #pragma unroll
    for (int j=0;j<8;j++) dp[j] = (f16)s[j];
  } else if (idx < 38912){             // e1 frag: [ks][mt][lane][8]
    int j2 = idx - 30720;
    int lane = j2&63, mt = (j2>>6)&15, ks = j2>>10;
    int m = mt*16 + (lane&15);
    int k = ks*32 + (lane>>4)*8;
    const float* s = e1w + (size_t)m*SKC + k;
    f16* dp = e1f + (size_t)j2*8;
    #pragma unroll
    for (int j=0;j<8;j++) dp[j] = (f16)s[j];
  } else if (idx < 47104){             // e2 frag
    int j2 = idx - 38912;
    int lane = j2&63, mt = (j2>>6)&15, ks = j2>>10;
    int m = mt*16 + (lane&15);
    int k = ks*32 + (lane>>4)*8;
    const float* s = e2w + (size_t)m*SKC + k;
    f16* dp = e2f + (size_t)j2*8;
    #pragma unroll
    for (int j=0;j<8;j++) dp[j] = (f16)s[j];
  } else if (idx < 77824){             // filt pairs: [i][co][ci] (2 taps)
    int j2 = idx - 47104;
    const float* s = fw + (size_t)j2*2;
    f16x2 p; p.x = (f16)s[0]; p.y = (f16)s[1];
    fgp[j2] = __builtin_bit_cast(uint32_t, p);
  } else if (idx < 108544){            // gate pairs
    int j2 = idx - 77824;
    const float* s = gw + (size_t)j2*2;
    f16x2 p; p.x = (f16)s[0]; p.y = (f16)s[1];
    ggp[j2] = __builtin_bit_cast(uint32_t, p);
  } else if (idx < 123904){            // res pairs
    int j2 = idx - 108544;
    int i = j2 >> 9, c = (j2>>4)&31, j = j2&15;
    const float* s = rw + ((size_t)i*NC + c)*NC + 2*j;
    f16x2 p; p.x = (f16)s[0]; p.y = (f16)s[1];
    rwp[j2] = __builtin_bit_cast(uint32_t, p);
  }
}

// ---------------- per-column layer math, 4 independent fdot2 chains ---------
__device__ __forceinline__ void layer_core(
    const uint4* A4p, const uint4* B4p,
    const uint32_t* __restrict__ fp0, const uint32_t* __restrict__ gp0,
    const uint32_t* __restrict__ rp0,
    uint32_t* __restrict__ zp, uint32_t* __restrict__ xo){
  uint32_t Bw[16], xp[32];
  {
    uint4 A4[4], B4[4];
    #pragma unroll
    for (int q=0;q<4;q++){ A4[q] = A4p[q]; B4[q] = B4p[q]; }
    uint32_t Aw[16];
    #pragma unroll
    for (int q=0;q<4;q++){
      Aw[4*q+0]=A4[q].x; Aw[4*q+1]=A4[q].y; Aw[4*q+2]=A4[q].z; Aw[4*q+3]=A4[q].w;
      Bw[4*q+0]=B4[q].x; Bw[4*q+1]=B4[q].y; Bw[4*q+2]=B4[q].z; Bw[4*q+3]=B4[q].w;
    }
    #pragma unroll
    for (int wd=0; wd<16; wd++){
      uint32_t a = Aw[wd], bb = Bw[wd];
      xp[2*wd]   = (a & 0xffffu) | (bb << 16);
      xp[2*wd+1] = (a >> 16) | (bb & 0xffff0000u);
    }
  }
  float zprev = 0.f;
  #pragma unroll
  for (int co=0; co<32; co++){
    const uint32_t* fp = fp0 + co*32;
    const uint32_t* gp = gp0 + co*32;
    float f0=0.f, f1=0.f, g0=0.f, g1=0.f;
    #pragma unroll
    for (int ci=0; ci<16; ci++){
      f0 = fdot2c(fp[ci],    xp[ci],    f0);
      g0 = fdot2c(gp[ci],    xp[ci],    g0);
      f1 = fdot2c(fp[ci+16], xp[ci+16], f1);
      g1 = fdot2c(gp[ci+16], xp[ci+16], g1);
    }
    float f = f0+f1, g = g0+g1;
    f = fminf(fmaxf(f, -30.f), 30.f);
    g = fminf(fmaxf(g, -30.f), 30.f);
    float ef = __expf(-2.f*f);
    float th = (1.f - ef) * frcp(1.f + ef);
    float sg = frcp(1.f + __expf(-g));
    float zc = th * sg;
    if (co & 1){
      f16x2 p; p.x = (f16)zprev; p.y = (f16)zc;
      zp[co>>1] = __builtin_bit_cast(uint32_t, p);
    } else {
      zprev = zc;
    }
  }
  #pragma unroll
  for (int j=0;j<16;j++){
    f16x2 bh = __builtin_bit_cast(f16x2, Bw[j]);
    float a0 = (float)bh.x, a1 = (float)bh.y;
    float a0b = 0.f, a1b = 0.f;
    const uint32_t* r0 = rp0 + (2*j)*16;
    const uint32_t* r1 = rp0 + (2*j+1)*16;
    #pragma unroll
    for (int k=0;k<8;k++){
      a0  = fdot2c(r0[k],   zp[k],   a0);
      a1  = fdot2c(r1[k],   zp[k],   a1);
      a0b = fdot2c(r0[k+8], zp[k+8], a0b);
      a1b = fdot2c(r1[k+8], zp[k+8], a1b);
    }
    f16x2 p; p.x = (f16)(a0+a0b); p.y = (f16)(a1+a1b);
    xo[j] = __builtin_bit_cast(uint32_t, p);
  }
}

// ---------------- fused 7-layer group (d=1..64), 128-col blocks -------------
struct Trim7 { int t[7]; };

__global__ __launch_bounds__(256, 3) void group7k(
    const f16* __restrict__ xin, const float* __restrict__ y,
    const float* __restrict__ cw, const float* __restrict__ cb, int tc0,
    f16* __restrict__ xout,
    f16* __restrict__ zbase, int g0, int Lfinal, int TcAct,
    const uint32_t* __restrict__ fgp, const uint32_t* __restrict__ ggp,
    const uint32_t* __restrict__ rwp, Trim7 trims){
  __shared__ uint4 xb[2][256*4];   // [256 pos][64B], 32.8 KB
  int tid = threadIdx.x, b = blockIdx.y, o0 = blockIdx.x*128;
  int Cf = Lfinal - o0; if (Cf > 128) Cf = 128;
  int Cin = Cf + 127;
  if (tid < Cin){
    uint4* dst = &xb[0][tid*4];
    if (y != nullptr){
      float yv = y[(size_t)b*T0 + tc0 + o0 + tid];
      uint32_t w[16];
      #pragma unroll
      for (int j=0;j<16;j++){
        f16x2 p;
        p.x = (f16)fmaf(cw[2*j],   yv, cb[2*j]);
        p.y = (f16)fmaf(cw[2*j+1], yv, cb[2*j+1]);
        w[j] = __builtin_bit_cast(uint32_t, p);
      }
      dst[0] = make_uint4(w[0],w[1],w[2],w[3]);
      dst[1] = make_uint4(w[4],w[5],w[6],w[7]);
      dst[2] = make_uint4(w[8],w[9],w[10],w[11]);
      dst[3] = make_uint4(w[12],w[13],w[14],w[15]);
    } else {
      const uint4* src = (const uint4*)(xin + ((size_t)b*XPB + o0 + tid)*NC);
      dst[0]=src[0]; dst[1]=src[1]; dst[2]=src[2]; dst[3]=src[3];
    }
  }
  __syncthreads();
  int cur = 0;
  #pragma unroll 1
  for (int li = 0; li < 7; li++){
    int d = 1 << li;
    int count = Cf + 128 - (2 << li);
    const uint32_t* fp0 = fgp + (size_t)(g0+li)*1024;
    const uint32_t* gp0 = ggp + (size_t)(g0+li)*1024;
    const uint32_t* rp0 = rwp + (size_t)(g0+li)*512;
    f16* zl = zbase + (size_t)(g0+li)*ZLS + (size_t)b*TC*NC;
    int trim = trims.t[li];
    if (tid < count){
      uint32_t zp[16], xo[16];
      layer_core(&xb[cur][tid*4], &xb[cur][(tid+d)*4], fp0, gp0, rp0, zp, xo);
      int lz = o0 + tid - trim;
      if (lz >= 0 && lz < TcAct){
        uint4* zo = (uint4*)(zl + (size_t)lz*NC);
        zo[0] = make_uint4(zp[0],zp[1],zp[2],zp[3]);
        zo[1] = make_uint4(zp[4],zp[5],zp[6],zp[7]);
        zo[2] = make_uint4(zp[8],zp[9],zp[10],zp[11]);
        zo[3] = make_uint4(zp[12],zp[13],zp[14],zp[15]);
      }
      uint4* D = &xb[cur^1][tid*4];
      D[0] = make_uint4(xo[0],xo[1],xo[2],xo[3]);
      D[1] = make_uint4(xo[4],xo[5],xo[6],xo[7]);
      D[2] = make_uint4(xo[8],xo[9],xo[10],xo[11]);
      D[3] = make_uint4(xo[12],xo[13],xo[14],xo[15]);
    }
    __syncthreads();
    cur ^= 1;
  }
  if (tid < Cf){
    uint4* dst = (uint4*)(xout + ((size_t)b*XPB + o0 + tid)*NC);
    const uint4* src = &xb[cur][tid*4];
    dst[0]=src[0]; dst[1]=src[1]; dst[2]=src[2]; dst[3]=src[3];
  }
}

// ---------------- single dilated layer (d=128/256/512) ----------------
__global__ __launch_bounds__(256, 2) void layer_single(
    const f16* __restrict__ xin, f16* __restrict__ xout, f16* __restrict__ zl,
    const uint32_t* __restrict__ fp0, const uint32_t* __restrict__ gp0,
    const uint32_t* __restrict__ rp0,
    int Tout, int d, int trim){
  int t = blockIdx.x*256 + threadIdx.x;
  int b = blockIdx.y;
  if (t >= Tout) return;
  const uint4* xa = (const uint4*)(xin + ((size_t)b*XPB + t)*NC);
  const uint4* xbp = (const uint4*)(xin + ((size_t)b*XPB + t + d)*NC);
  uint32_t zp[16], xo[16];
  layer_core(xa, xbp, fp0, gp0, rp0, zp, xo);
  if (t >= trim){
    uint4* zo = (uint4*)(zl + ((size_t)b*TC + (t - trim))*NC);
    zo[0] = make_uint4(zp[0],zp[1],zp[2],zp[3]);
    zo[1] = make_uint4(zp[4],zp[5],zp[6],zp[7]);
    zo[2] = make_uint4(zp[8],zp[9],zp[10],zp[11]);
    zo[3] = make_uint4(zp[12],zp[13],zp[14],zp[15]);
  }
  uint4* xod = (uint4*)(xout + ((size_t)b*XPB + t)*NC);
  xod[0] = make_uint4(xo[0],xo[1],xo[2],xo[3]);
  xod[1] = make_uint4(xo[4],xo[5],xo[6],xo[7]);
  xod[2] = make_uint4(xo[8],xo[9],xo[10],xo[11]);
  xod[3] = make_uint4(xo[12],xo[13],xo[14],xo[15]);
}

// ------- fused skip(K=960) -> relu -> end1 -> relu -> end2, write f32 -------
__global__ __launch_bounds__(256) void skipend(
    const f16* __restrict__ zbase,
    const f16* __restrict__ wsk, const f16* __restrict__ e1f,
    const float* __restrict__ e1b, const f16* __restrict__ e2f,
    const float* __restrict__ e2b, float* __restrict__ out,
    int tc0, int TcAct){
  __shared__ uint4 smem4[4224];               // 67,584 B
  f16* Ab = (f16*)smem4;                      // phase1: [2][8192]
  f16* Zb = (f16*)smem4 + 32768/2;            // phase1: [2][2048]
  f16* sA = (f16*)smem4;                      // phase2+: [64][264]
  f16* sB = (f16*)smem4 + 33792/2;
  int tid = threadIdx.x, b = blockIdx.y, t0 = blockIdx.x*64;
  int w = tid>>6, lane = tid&63;
  int tl = w*16 + (lane&15);
  int kq = (lane>>4)*8;
  int rq = (lane>>4)*4;

  const uint4* wsk4 = (const uint4*)wsk;
  uint4 st[5];
  auto stLoad = [&](int l){
    const uint4* s = wsk4 + (size_t)l*1024 + tid*4;
    st[0]=s[0]; st[1]=s[1]; st[2]=s[2]; st[3]=s[3];
    int t = tid>>2, c8 = tid&3;
    st[4] = *(const uint4*)(zbase + (size_t)l*ZLS + ((size_t)b*TC + t0 + t)*NC + c8*8);
  };
  auto stStore = [&](int l){
    int buf = l & 1;
    uint4* d = (uint4*)(Ab + buf*8192) + tid*4;
    d[0]=st[0]; d[1]=st[1]; d[2]=st[2]; d[3]=st[3];
    *((uint4*)(Zb + buf*2048) + tid) = st[4];
  };

  f32x4 acc[16];
  #pragma unroll
  for (int mt=0; mt<16; mt++) acc[mt] = f32x4{0.f,0.f,0.f,0.f};

  stLoad(0); stStore(0);
  for (int l = 0; l < NL; l++){
    __syncthreads();
    if (l+1 < NL) stLoad(l+1);               // issue early
    int buf = l & 1;
    f16x8 bf = *(const f16x8*)(Zb + buf*2048 + (size_t)(tl*32 + kq));
    const f16x8* ap = (const f16x8*)(Ab + buf*8192) + lane;
    #pragma unroll
    for (int mt=0; mt<16; mt++)
      acc[mt] = MFMA16(ap[mt*64], bf, acc[mt]);
    if (l+1 < NL) stStore(l+1);              // write late (hidden under MFMA)
  }
  __syncthreads();
  // phase2: relu(skip) -> sA [t][c]
  #pragma unroll
  for (int mt=0; mt<16; mt++)
    #pragma unroll
    for (int r=0;r<4;r++)
      sA[(size_t)tl*264 + mt*16 + rq + r] = (f16)fmaxf(acc[mt][r], 0.f);
  __syncthreads();
  // phase3: end1
  f32x4 a2[16];
  #pragma unroll
  for (int mt=0; mt<16; mt++) a2[mt] = f32x4{0.f,0.f,0.f,0.f};
  #pragma unroll
  for (int ks=0; ks<8; ks++){
    f16x8 bf = *(const f16x8*)&sA[(size_t)tl*264 + ks*32 + kq];
    const f16x8* wp = (const f16x8*)e1f + (size_t)(ks*16)*64 + lane;
    #pragma unroll
    for (int mt=0; mt<16; mt++)
      a2[mt] = MFMA16(wp[mt*64], bf, a2[mt]);
  }
  #pragma unroll
  for (int mt=0; mt<16; mt++){
    #pragma unroll
    for (int r=0;r<4;r++){
      int c = mt*16 + rq + r;
      sB[(size_t)tl*264 + c] = (f16)fmaxf(a2[mt][r] + e1b[c], 0.f);
    }
  }
  __syncthreads();
  // phase4: end2 + final write
  #pragma unroll
  for (int mt=0; mt<16; mt++) a2[mt] = f32x4{0.f,0.f,0.f,0.f};
  #pragma unroll
  for (int ks=0; ks<8; ks++){
    f16x8 bf = *(const f16x8*)&sB[(size_t)tl*264 + ks*32 + kq];
    const f16x8* wp = (const f16x8*)e2f + (size_t)(ks*16)*64 + lane;
    #pragma unroll
    for (int mt=0; mt<16; mt++)
      a2[mt] = MFMA16(wp[mt*64], bf, a2[mt]);
  }
  int tt = t0 + tl;
  if (tt < TcAct){
    #pragma unroll
    for (int mt=0; mt<16; mt++){
      #pragma unroll
      for (int r=0;r<4;r++){
        int c = mt*16 + rq + r;
        out[((size_t)b*SKC + c)*TF + tc0 + tt] = a2[mt][r] + e2b[c];
      }
    }
  }
}

extern "C" void kernel_launch(void* const* d_in, const int* in_sizes, int n_in,
                              void* d_out, int out_size, void* d_ws, size_t ws_size,
                              hipStream_t stream) {
  (void)in_sizes; (void)n_in; (void)out_size; (void)ws_size;
  const float* y   = (const float*)d_in[0];
  const float* cw  = (const float*)d_in[1];
  const float* cb  = (const float*)d_in[2];
  const float* fw  = (const float*)d_in[3];
  const float* gw  = (const float*)d_in[4];
  const float* rw  = (const float*)d_in[5];
  const float* sw  = (const float*)d_in[6];
  const float* e1w = (const float*)d_in[7];
  const float* e1b = (const float*)d_in[8];
  const float* e2w = (const float*)d_in[9];
  const float* e2b = (const float*)d_in[10];
  float* out = (float*)d_out;
  char* ws = (char*)d_ws;

  // ws layout, total 86,781,952 B (proven ws >= 89,403,392)
  f16* wsk      = (f16*)(ws);                       //   491,520
  f16* e1f      = (f16*)(ws +   491520);            //   131,072
  f16* e2f      = (f16*)(ws +   622592);            //   131,072
  uint32_t* fgp = (uint32_t*)(ws +  753664);        //   122,880
  uint32_t* ggp = (uint32_t*)(ws +  876544);        //   122,880
  uint32_t* rwp = (uint32_t*)(ws +  999424);        //    61,440
  f16* xpA      = (f16*)(ws + 1060864);             // 5,505,024
  f16* xpB      = (f16*)(ws + 6565888);             // 5,505,024
  f16* zstack   = (f16*)(ws + 12070912);            // 74,711,040

  int S[NL+1]; S[NL] = 0;
  for (int i = NL-1; i >= 0; i--) S[i] = S[i+1] + (1 << (i % 10));

  prep2<<<dim3(484), 256, 0, stream>>>(sw, e1w, e2w, fw, gw, rw,
                                       wsk, e1f, e2f, fgp, ggp, rwp);

  f16* bufs[2] = {xpA, xpB};
  for (int tc0 = 0; tc0 < TF; tc0 += TC){
    int TcAct = TF - tc0; if (TcAct > TC) TcAct = TC;
    int cur = 0;
    for (int s = 0; s < 3; s++){
      int g0 = s*10;
      Trim7 tr;
      for (int li = 0; li < 7; li++) tr.t[li] = S[g0+li+1];
      int Lfinal = TcAct + S[g0+7];
      const f16* gin = (s == 0) ? (const f16*)nullptr : bufs[cur];
      const float* yArg = (s == 0) ? y : (const float*)nullptr;
      int nxt = (s == 0) ? 0 : (cur ^ 1);
      group7k<<<dim3((Lfinal + 127)/128, NB), 256, 0, stream>>>(
          gin, yArg, cw, cb, tc0, bufs[nxt], zstack, g0, Lfinal, TcAct,
          fgp, ggp, rwp, tr);
      cur = nxt;
      for (int i = g0+7; i <= g0+9; i++){
        int d = 1 << (i % 10);
        int Tout = TcAct + S[i+1];
        layer_single<<<dim3((Tout + 255)/256, NB), 256, 0, stream>>>(
            bufs[cur], bufs[cur^1], zstack + (size_t)i*ZLS,
            fgp + (size_t)i*1024, ggp + (size_t)i*1024, rwp + (size_t)i*512,
            Tout, d, S[i+1]);
        cur ^= 1;
      }
    }
    skipend<<<dim3((TcAct + 63)/64, NB), 256, 0, stream>>>(
        zstack, wsk, e1f, e1b, e2f, e2b, out, tc0, TcAct);
  }
}

// Round 7
// 2171.550 us; speedup vs baseline: 3.6863x; 3.2945x over previous
//
#include <hip/hip_runtime.h>
#include <hip/hip_bf16.h>
#include <cstdint>

#define NB 16
#define NC 32
#define T0 16384
#define NL 30
#define SKC 256
#define TF 13315
#define TC 2432           // time-chunk (final coords)
#define XPB 5376          // ping-pong row capacity (>= TC + 2942)
#define ZLS ((size_t)NB*TC*NC)   // f16 elements per z layer
#define WGRP 192          // final cols per group block
#define XBC 384           // staged col capacity in group LDS
#define XBS 20            // x LDS col stride in u32 (80B, conflict-free)
#define ZBS 20            // zbuf row stride in u32 (80B)

typedef _Float16 f16;
typedef _Float16 f16x2 __attribute__((ext_vector_type(2)));
typedef _Float16 f16x8 __attribute__((ext_vector_type(8)));
typedef float f32x4 __attribute__((ext_vector_type(4)));
typedef uint32_t u32;

#define MFMA16(a,b,c) __builtin_amdgcn_mfma_f32_16x16x32_f16(a,b,c,0,0,0)

#define SCF (-2.88539008f)   // -2*log2(e): ef = e^-2f = 2^(SCF*f)
#define SCG (-1.44269504f)   // -log2(e):   eg = e^-g  = 2^(SCG*g)
#define CLF 86.6f
#define CLG 43.3f

__device__ __forceinline__ float frcp(float x){
#if __has_builtin(__builtin_amdgcn_rcpf)
  return __builtin_amdgcn_rcpf(x);
#else
  return 1.f/x;
#endif
}
__device__ __forceinline__ float fexp2(float x){
#if __has_builtin(__builtin_amdgcn_exp2f)
  return __builtin_amdgcn_exp2f(x);
#else
  return exp2f(x);
#endif
}
__device__ __forceinline__ u32 perm_lo(u32 a, u32 b){   // (a.lo16 | b.lo16<<16)
#if __has_builtin(__builtin_amdgcn_perm)
  return __builtin_amdgcn_perm(b, a, 0x05040100u);
#else
  return (a & 0xffffu) | (b << 16);
#endif
}
__device__ __forceinline__ u32 perm_hi(u32 a, u32 b){   // (a.hi16 | b.hi16<<16)
#if __has_builtin(__builtin_amdgcn_perm)
  return __builtin_amdgcn_perm(b, a, 0x07060302u);
#else
  return (a >> 16) | (b & 0xffff0000u);
#endif
}
__device__ __forceinline__ u32 pk2(float x, float y){
#if __has_builtin(__builtin_amdgcn_cvt_pkrtz)
  return __builtin_bit_cast(u32, __builtin_amdgcn_cvt_pkrtz(x, y));
#else
  f16x2 r; r.x = (f16)x; r.y = (f16)y;
  return __builtin_bit_cast(u32, r);
#endif
}

// ---------------- prep: weights -> f16 fragment order / pair layouts --------
// fgp/ggp rows are exactly MFMA A-fragments for k=2*ci+tap ordering (scaled
// into exp2 domain); rwp rows are A-fragments for the res conv.
__global__ __launch_bounds__(256) void prep3(
    const float* __restrict__ sw, const float* __restrict__ e1w,
    const float* __restrict__ e2w, const float* __restrict__ fw,
    const float* __restrict__ gw, const float* __restrict__ rw,
    f16* __restrict__ wsk, f16* __restrict__ e1f, f16* __restrict__ e2f,
    u32* __restrict__ fgp, u32* __restrict__ ggp, u32* __restrict__ rwp){
  int idx = blockIdx.x*256 + threadIdx.x;
  if (idx < 30720){                    // skip weights frag: [i][mt][lane][8]
    int lane = idx & 63, mt = (idx>>6)&15, i = idx>>10;
    int m = mt*16 + (lane&15);
    int kl = (lane>>4)*8;
    const float* s = sw + ((size_t)i*SKC + m)*NC + kl;
    f16* dp = wsk + (size_t)idx*8;
    #pragma unroll
    for (int j=0;j<8;j++) dp[j] = (f16)s[j];
  } else if (idx < 38912){             // e1 frag: [ks][mt][lane][8]
    int j2 = idx - 30720;
    int lane = j2&63, mt = (j2>>6)&15, ks = j2>>10;
    int m = mt*16 + (lane&15);
    int k = ks*32 + (lane>>4)*8;
    const float* s = e1w + (size_t)m*SKC + k;
    f16* dp = e1f + (size_t)j2*8;
    #pragma unroll
    for (int j=0;j<8;j++) dp[j] = (f16)s[j];
  } else if (idx < 47104){             // e2 frag
    int j2 = idx - 38912;
    int lane = j2&63, mt = (j2>>6)&15, ks = j2>>10;
    int m = mt*16 + (lane&15);
    int k = ks*32 + (lane>>4)*8;
    const float* s = e2w + (size_t)m*SKC + k;
    f16* dp = e2f + (size_t)j2*8;
    #pragma unroll
    for (int j=0;j<8;j++) dp[j] = (f16)s[j];
  } else if (idx < 77824){             // filt pairs, exp2-scaled
    int j2 = idx - 47104;
    const float* s = fw + (size_t)j2*2;
    f16x2 p; p.x = (f16)(s[0]*SCF); p.y = (f16)(s[1]*SCF);
    fgp[j2] = __builtin_bit_cast(u32, p);
  } else if (idx < 108544){            // gate pairs, exp2-scaled
    int j2 = idx - 77824;
    const float* s = gw + (size_t)j2*2;
    f16x2 p; p.x = (f16)(s[0]*SCG); p.y = (f16)(s[1]*SCG);
    ggp[j2] = __builtin_bit_cast(u32, p);
  } else if (idx < 123904){            // res rows: rw[i][c][0..31] consecutive
    int j2 = idx - 108544;
    int i = j2 >> 9, c = (j2>>4)&31, j = j2&15;
    const float* s = rw + ((size_t)i*NC + c)*NC + 2*j;
    f16x2 p; p.x = (f16)s[0]; p.y = (f16)s[1];
    rwp[j2] = __builtin_bit_cast(u32, p);
  }
}

// ---------------- per-layer weight fragments ----------------
struct LW { f16x8 af[4]; f16x8 ag[4]; f16x8 ar[2]; };
__device__ __forceinline__ void lw_load(LW& w, const u32* __restrict__ fp,
    const u32* __restrict__ gp, const u32* __restrict__ rp, int lane){
  int m = lane & 15, q4 = (lane >> 4) * 4;
  #pragma unroll
  for (int mh = 0; mh < 2; mh++){
    #pragma unroll
    for (int kc = 0; kc < 2; kc++){
      w.af[mh*2+kc] = *(const f16x8*)&fp[(mh*16+m)*32 + kc*16 + q4];
      w.ag[mh*2+kc] = *(const f16x8*)&gp[(mh*16+m)*32 + kc*16 + q4];
    }
    w.ar[mh] = *(const f16x8*)&rp[(mh*16+m)*16 + q4];
  }
}

// ---------------- 16-col tile engine: conv->gate->res via MFMA --------------
// a0/a1 = x[t] ch quads (q*4, 16+q*4); b0/b1 = x[t+d] same (also residual).
// Leaves z tile in zbw ([16 t][40 f16] rows); returns packed x_out.
__device__ __forceinline__ void tile_core(const LW& w,
    uint2 a0, uint2 a1, uint2 b0, uint2 b1,
    u32* zbw, int lane, uint2& xo0, uint2& xo1){
  uint4 B0u = make_uint4(perm_lo(a0.x,b0.x), perm_hi(a0.x,b0.x),
                         perm_lo(a0.y,b0.y), perm_hi(a0.y,b0.y));
  uint4 B1u = make_uint4(perm_lo(a1.x,b1.x), perm_hi(a1.x,b1.x),
                         perm_lo(a1.y,b1.y), perm_hi(a1.y,b1.y));
  f16x8 B0 = __builtin_bit_cast(f16x8, B0u);
  f16x8 B1 = __builtin_bit_cast(f16x8, B1u);
  f32x4 z4 = {0.f,0.f,0.f,0.f};
  f32x4 fa0 = MFMA16(w.af[0], B0, z4); fa0 = MFMA16(w.af[1], B1, fa0);
  f32x4 fa1 = MFMA16(w.af[2], B0, z4); fa1 = MFMA16(w.af[3], B1, fa1);
  f32x4 ga0 = MFMA16(w.ag[0], B0, z4); ga0 = MFMA16(w.ag[1], B1, ga0);
  f32x4 ga1 = MFMA16(w.ag[2], B0, z4); ga1 = MFMA16(w.ag[3], B1, ga1);
  u32 zq[4];
  #pragma unroll
  for (int mh = 0; mh < 2; mh++){
    f32x4 fv = mh ? fa1 : fa0;
    f32x4 gv = mh ? ga1 : ga0;
    float zz[4];
    #pragma unroll
    for (int r = 0; r < 4; r++){
      float fc = fminf(fmaxf(fv[r], -CLF), CLF);
      float gc = fminf(fmaxf(gv[r], -CLG), CLG);
      float ef = fexp2(fc);
      float eg = fexp2(gc);
      zz[r] = (1.f - ef) * frcp((1.f + ef) * (1.f + eg));
    }
    zq[mh*2+0] = pk2(zz[0], zz[1]);
    zq[mh*2+1] = pk2(zz[2], zz[3]);
  }
  int t = lane & 15, q = lane >> 4;
  *(uint2*)&zbw[t*ZBS + q*2]     = make_uint2(zq[0], zq[1]);
  *(uint2*)&zbw[t*ZBS + 8 + q*2] = make_uint2(zq[2], zq[3]);
  f16x8 zB = *(const f16x8*)&zbw[t*ZBS + q*4];
  f32x4 r0 = MFMA16(w.ar[0], zB, z4);
  f32x4 r1 = MFMA16(w.ar[1], zB, z4);
  f16x2 b00 = __builtin_bit_cast(f16x2, b0.x);
  f16x2 b01 = __builtin_bit_cast(f16x2, b0.y);
  f16x2 b10 = __builtin_bit_cast(f16x2, b1.x);
  f16x2 b11 = __builtin_bit_cast(f16x2, b1.y);
  xo0.x = pk2(r0[0] + (float)b00.x, r0[1] + (float)b00.y);
  xo0.y = pk2(r0[2] + (float)b01.x, r0[3] + (float)b01.y);
  xo1.x = pk2(r1[0] + (float)b10.x, r1[1] + (float)b10.y);
  xo1.y = pk2(r1[2] + (float)b11.x, r1[3] + (float)b11.y);
}

// ---------------- fused 7-layer group (d=1..64), MFMA, 192-col blocks -------
struct Trim7 { int t[7]; };

__global__ __launch_bounds__(256, 2) void group7m(
    const f16* __restrict__ xin, const float* __restrict__ y,
    const float* __restrict__ cw, const float* __restrict__ cb, int tc0,
    f16* __restrict__ xout, f16* __restrict__ zbase, int g0,
    int Lfinal, int TcAct,
    const u32* __restrict__ fgp, const u32* __restrict__ ggp,
    const u32* __restrict__ rwp, Trim7 trims){
  __shared__ u32 xb[2][XBC*XBS];    // 61,440 B
  __shared__ u32 zbuf[4][16*ZBS];   //  5,120 B
  int tid = threadIdx.x, b = blockIdx.y, o0 = blockIdx.x*WGRP;
  int lane = tid & 63, widx = tid >> 6;
  int Cf = Lfinal - o0; if (Cf > WGRP) Cf = WGRP;
  int Cin = Cf + 127;
  // stage x_{g0} cols [o0, o0+Cin) (stack0: fused causal from y)
  for (int p = tid; p < Cin; p += 256){
    u32* dst = &xb[0][p*XBS];
    if (y != nullptr){
      float yv = y[(size_t)b*T0 + tc0 + o0 + p];
      #pragma unroll
      for (int j = 0; j < 16; j++)
        dst[j] = pk2(fmaf(cw[2*j], yv, cb[2*j]), fmaf(cw[2*j+1], yv, cb[2*j+1]));
    } else {
      const uint4* src = (const uint4*)(xin + ((size_t)b*XPB + o0 + p)*NC);
      uint4* d4 = (uint4*)dst;
      d4[0]=src[0]; d4[1]=src[1]; d4[2]=src[2]; d4[3]=src[3];
    }
  }
  __syncthreads();
  int cur = 0;
  #pragma unroll 1
  for (int li = 0; li < 7; li++){
    int d = 1 << li;
    int count = Cf + 128 - (2 << li);
    LW w;
    lw_load(w, fgp + (size_t)(g0+li)*1024, ggp + (size_t)(g0+li)*1024,
            rwp + (size_t)(g0+li)*512, lane);
    f16* zl = zbase + (size_t)(g0+li)*ZLS + (size_t)b*TC*NC;
    int trim = trims.t[li];
    int ntiles = (count + 15) >> 4;
    u32* zbw = zbuf[widx];
    for (int ti = widx; ti < ntiles; ti += 4){
      int t0 = ti*16;
      int c = t0 + (lane & 15), q = lane >> 4;
      const u32* xc = &xb[cur][c*XBS];
      const u32* xd = &xb[cur][(c+d)*XBS];
      uint2 a0 = *(const uint2*)&xc[q*2];
      uint2 a1 = *(const uint2*)&xc[8 + q*2];
      uint2 b0 = *(const uint2*)&xd[q*2];
      uint2 b1 = *(const uint2*)&xd[8 + q*2];
      uint2 xo0, xo1;
      tile_core(w, a0, a1, b0, b1, zbw, lane, xo0, xo1);
      u32* xn = &xb[cur^1][c*XBS];
      *(uint2*)&xn[q*2] = xo0;
      *(uint2*)&xn[8 + q*2] = xo1;
      // coalesced z store (transposed read from zbuf)
      int zr = lane >> 2, zc4 = (lane & 3) * 4;
      uint4 zv = *(const uint4*)&zbw[zr*ZBS + zc4];
      int p = t0 + zr;
      int lz = o0 + p - trim;
      if (p < count && lz >= 0 && lz < TcAct)
        *(uint4*)(zl + (size_t)lz*NC + zc4*2) = zv;
    }
    __syncthreads();
    cur ^= 1;
  }
  for (int p = tid; p < Cf; p += 256){
    const uint4* s = (const uint4*)&xb[cur][p*XBS];
    uint4* dd = (uint4*)(xout + ((size_t)b*XPB + o0 + p)*NC);
    dd[0]=s[0]; dd[1]=s[1]; dd[2]=s[2]; dd[3]=s[3];
  }
}

// ---------------- single dilated layer (d=128/256/512), MFMA, global --------
__global__ __launch_bounds__(256, 4) void singlem(
    const f16* __restrict__ xin, f16* __restrict__ xout, f16* __restrict__ zl,
    const u32* __restrict__ fp, const u32* __restrict__ gp,
    const u32* __restrict__ rp, int Tout, int d, int trim, int TcAct){
  __shared__ u32 zbuf[4][16*ZBS];
  int tid = threadIdx.x, b = blockIdx.y;
  int lane = tid & 63, widx = tid >> 6;
  int t0 = (blockIdx.x*4 + widx) * 16;
  if (t0 >= Tout) return;
  LW w;
  lw_load(w, fp, gp, rp, lane);
  int c = t0 + (lane & 15), q = lane >> 4;
  const f16* xc = xin + ((size_t)b*XPB + c)*NC;
  const f16* xd = xc + (size_t)d*NC;
  uint2 a0 = *(const uint2*)(xc + q*4);
  uint2 a1 = *(const uint2*)(xc + 16 + q*4);
  uint2 b0 = *(const uint2*)(xd + q*4);
  uint2 b1 = *(const uint2*)(xd + 16 + q*4);
  uint2 xo0, xo1;
  tile_core(w, a0, a1, b0, b1, zbuf[widx], lane, xo0, xo1);
  if (c < Tout){
    f16* xoc = xout + ((size_t)b*XPB + c)*NC;
    *(uint2*)(xoc + q*4) = xo0;
    *(uint2*)(xoc + 16 + q*4) = xo1;
  }
  int zr = lane >> 2, zc4 = (lane & 3) * 4;
  uint4 zv = *(const uint4*)&zbuf[widx][zr*ZBS + zc4];
  int p = t0 + zr, lz = p - trim;
  if (p < Tout && lz >= 0 && lz < TcAct)
    *(uint4*)(zl + ((size_t)b*TC + lz)*NC + zc4*2) = zv;
}

// ------- fused skip(K=960) -> relu -> end1 -> relu -> end2, write f32 -------
__global__ __launch_bounds__(256) void skipend(
    const f16* __restrict__ zbase,
    const f16* __restrict__ wsk, const f16* __restrict__ e1f,
    const float* __restrict__ e1b, const f16* __restrict__ e2f,
    const float* __restrict__ e2b, float* __restrict__ out,
    int tc0, int TcAct){
  __shared__ uint4 smem4[4224];               // 67,584 B
  f16* Ab = (f16*)smem4;                      // phase1: [2][8192]
  f16* Zb = (f16*)smem4 + 32768/2;            // phase1: [2][2048]
  f16* sA = (f16*)smem4;                      // phase2+: [64][264]
  f16* sB = (f16*)smem4 + 33792/2;
  int tid = threadIdx.x, b = blockIdx.y, t0 = blockIdx.x*64;
  int w = tid>>6, lane = tid&63;
  int tl = w*16 + (lane&15);
  int kq = (lane>>4)*8;
  int rq = (lane>>4)*4;

  const uint4* wsk4 = (const uint4*)wsk;
  uint4 st[5];
  auto stLoad = [&](int l){
    const uint4* s = wsk4 + (size_t)l*1024 + tid*4;
    st[0]=s[0]; st[1]=s[1]; st[2]=s[2]; st[3]=s[3];
    int t = tid>>2, c8 = tid&3;
    st[4] = *(const uint4*)(zbase + (size_t)l*ZLS + ((size_t)b*TC + t0 + t)*NC + c8*8);
  };
  auto stStore = [&](int l){
    int buf = l & 1;
    uint4* d = (uint4*)(Ab + buf*8192) + tid*4;
    d[0]=st[0]; d[1]=st[1]; d[2]=st[2]; d[3]=st[3];
    *((uint4*)(Zb + buf*2048) + tid) = st[4];
  };

  f32x4 acc[16];
  #pragma unroll
  for (int mt=0; mt<16; mt++) acc[mt] = f32x4{0.f,0.f,0.f,0.f};

  stLoad(0); stStore(0);
  for (int l = 0; l < NL; l++){
    __syncthreads();
    if (l+1 < NL) stLoad(l+1);               // issue early
    int buf = l & 1;
    f16x8 bf = *(const f16x8*)(Zb + buf*2048 + (size_t)(tl*32 + kq));
    const f16x8* ap = (const f16x8*)(Ab + buf*8192) + lane;
    #pragma unroll
    for (int mt=0; mt<16; mt++)
      acc[mt] = MFMA16(ap[mt*64], bf, acc[mt]);
    if (l+1 < NL) stStore(l+1);              // write late (hidden under MFMA)
  }
  __syncthreads();
  // phase2: relu(skip) -> sA [t][c]
  #pragma unroll
  for (int mt=0; mt<16; mt++)
    #pragma unroll
    for (int r=0;r<4;r++)
      sA[(size_t)tl*264 + mt*16 + rq + r] = (f16)fmaxf(acc[mt][r], 0.f);
  __syncthreads();
  // phase3: end1
  f32x4 a2[16];
  #pragma unroll
  for (int mt=0; mt<16; mt++) a2[mt] = f32x4{0.f,0.f,0.f,0.f};
  #pragma unroll
  for (int ks=0; ks<8; ks++){
    f16x8 bf = *(const f16x8*)&sA[(size_t)tl*264 + ks*32 + kq];
    const f16x8* wp = (const f16x8*)e1f + (size_t)(ks*16)*64 + lane;
    #pragma unroll
    for (int mt=0; mt<16; mt++)
      a2[mt] = MFMA16(wp[mt*64], bf, a2[mt]);
  }
  #pragma unroll
  for (int mt=0; mt<16; mt++){
    #pragma unroll
    for (int r=0;r<4;r++){
      int c = mt*16 + rq + r;
      sB[(size_t)tl*264 + c] = (f16)fmaxf(a2[mt][r] + e1b[c], 0.f);
    }
  }
  __syncthreads();
  // phase4: end2 + final write
  #pragma unroll
  for (int mt=0; mt<16; mt++) a2[mt] = f32x4{0.f,0.f,0.f,0.f};
  #pragma unroll
  for (int ks=0; ks<8; ks++){
    f16x8 bf = *(const f16x8*)&sB[(size_t)tl*264 + ks*32 + kq];
    const f16x8* wp = (const f16x8*)e2f + (size_t)(ks*16)*64 + lane;
    #pragma unroll
    for (int mt=0; mt<16; mt++)
      a2[mt] = MFMA16(wp[mt*64], bf, a2[mt]);
  }
  int tt = t0 + tl;
  if (tt < TcAct){
    #pragma unroll
    for (int mt=0; mt<16; mt++){
      #pragma unroll
      for (int r=0;r<4;r++){
        int c = mt*16 + rq + r;
        out[((size_t)b*SKC + c)*TF + tc0 + tt] = a2[mt][r] + e2b[c];
      }
    }
  }
}

extern "C" void kernel_launch(void* const* d_in, const int* in_sizes, int n_in,
                              void* d_out, int out_size, void* d_ws, size_t ws_size,
                              hipStream_t stream) {
  (void)in_sizes; (void)n_in; (void)out_size; (void)ws_size;
  const float* y   = (const float*)d_in[0];
  const float* cw  = (const float*)d_in[1];
  const float* cb  = (const float*)d_in[2];
  const float* fw  = (const float*)d_in[3];
  const float* gw  = (const float*)d_in[4];
  const float* rw  = (const float*)d_in[5];
  const float* sw  = (const float*)d_in[6];
  const float* e1w = (const float*)d_in[7];
  const float* e1b = (const float*)d_in[8];
  const float* e2w = (const float*)d_in[9];
  const float* e2b = (const float*)d_in[10];
  float* out = (float*)d_out;
  char* ws = (char*)d_ws;

  // ws layout, total 86,781,952 B (proven ws >= 89,403,392)
  f16* wsk  = (f16*)(ws);                       //   491,520
  f16* e1f  = (f16*)(ws +   491520);            //   131,072
  f16* e2f  = (f16*)(ws +   622592);            //   131,072
  u32* fgp  = (u32*)(ws +  753664);             //   122,880
  u32* ggp  = (u32*)(ws +  876544);             //   122,880
  u32* rwp  = (u32*)(ws +  999424);             //    61,440
  f16* xpA  = (f16*)(ws + 1060864);             // 5,505,024
  f16* xpB  = (f16*)(ws + 6565888);             // 5,505,024
  f16* zstack = (f16*)(ws + 12070912);          // 74,711,040

  int S[NL+1]; S[NL] = 0;
  for (int i = NL-1; i >= 0; i--) S[i] = S[i+1] + (1 << (i % 10));

  prep3<<<dim3(484), 256, 0, stream>>>(sw, e1w, e2w, fw, gw, rw,
                                       wsk, e1f, e2f, fgp, ggp, rwp);

  f16* bufs[2] = {xpA, xpB};
  for (int tc0 = 0; tc0 < TF; tc0 += TC){
    int TcAct = TF - tc0; if (TcAct > TC) TcAct = TC;
    int cur = 0;
    for (int s = 0; s < 3; s++){
      int g0 = s*10;
      Trim7 tr;
      for (int li = 0; li < 7; li++) tr.t[li] = S[g0+li+1];
      int Lfinal = TcAct + S[g0+7];
      const f16* gin = (s == 0) ? (const f16*)nullptr : bufs[cur];
      const float* yArg = (s == 0) ? y : (const float*)nullptr;
      int nxt = (s == 0) ? 0 : (cur ^ 1);
      group7m<<<dim3((Lfinal + WGRP-1)/WGRP, NB), 256, 0, stream>>>(
          gin, yArg, cw, cb, tc0, bufs[nxt], zstack, g0, Lfinal, TcAct,
          fgp, ggp, rwp, tr);
      cur = nxt;
      for (int i = g0+7; i <= g0+9; i++){
        int d = 1 << (i % 10);
        int Tout = TcAct + S[i+1];
        singlem<<<dim3((Tout + 63)/64, NB), 256, 0, stream>>>(
            bufs[cur], bufs[cur^1], zstack + (size_t)i*ZLS,
            fgp + (size_t)i*1024, ggp + (size_t)i*1024, rwp + (size_t)i*512,
            Tout, d, S[i+1], TcAct);
        cur ^= 1;
      }
    }
    skipend<<<dim3((TcAct + 63)/64, NB), 256, 0, stream>>>(
        zstack, wsk, e1f, e1b, e2f, e2b, out, tc0, TcAct);
  }
}

// Round 8
// 1412.029 us; speedup vs baseline: 5.6691x; 1.5379x over previous
//
#include <hip/hip_runtime.h>
#include <hip/hip_bf16.h>
#include <cstdint>

#define NB 16
#define NC 32
#define T0 16384
#define NL 30
#define SKC 256
#define TF 13315
#define TC 2432           // time-chunk (final coords)
#define XPB 5376          // ping-pong row capacity (>= TC + 2942)
#define ZLS ((size_t)NB*TC*NC)   // f16 elements per z layer
#define WGRP 192          // final cols per group block
#define XBC 384           // staged col capacity in group LDS
#define XBS 20            // x LDS col stride in u32 (80B, conflict-free)
#define ZBS 20            // zbuf row stride in u32 (80B)

typedef _Float16 f16;
typedef _Float16 f16x2 __attribute__((ext_vector_type(2)));
typedef _Float16 f16x8 __attribute__((ext_vector_type(8)));
typedef float f32x4 __attribute__((ext_vector_type(4)));
typedef uint32_t u32;

#define MFMA16(a,b,c) __builtin_amdgcn_mfma_f32_16x16x32_f16(a,b,c,0,0,0)

#define SCF (-2.88539008f)   // -2*log2(e): ef = e^-2f = 2^(SCF*f)
#define SCG (-1.44269504f)   // -log2(e):   eg = e^-g  = 2^(SCG*g)
#define CLF 86.6f
#define CLG 43.3f

__device__ __forceinline__ float frcp(float x){
#if __has_builtin(__builtin_amdgcn_rcpf)
  return __builtin_amdgcn_rcpf(x);
#else
  return 1.f/x;
#endif
}
__device__ __forceinline__ float fexp2(float x){
#if __has_builtin(__builtin_amdgcn_exp2f)
  return __builtin_amdgcn_exp2f(x);
#else
  return exp2f(x);
#endif
}
__device__ __forceinline__ u32 perm_lo(u32 a, u32 b){   // (a.lo16 | b.lo16<<16)
#if __has_builtin(__builtin_amdgcn_perm)
  return __builtin_amdgcn_perm(b, a, 0x05040100u);
#else
  return (a & 0xffffu) | (b << 16);
#endif
}
__device__ __forceinline__ u32 perm_hi(u32 a, u32 b){   // (a.hi16 | b.hi16<<16)
#if __has_builtin(__builtin_amdgcn_perm)
  return __builtin_amdgcn_perm(b, a, 0x07060302u);
#else
  return (a >> 16) | (b & 0xffff0000u);
#endif
}
__device__ __forceinline__ u32 pk2(float x, float y){
#if __has_builtin(__builtin_amdgcn_cvt_pkrtz)
  return __builtin_bit_cast(u32, __builtin_amdgcn_cvt_pkrtz(x, y));
#else
  f16x2 r; r.x = (f16)x; r.y = (f16)y;
  return __builtin_bit_cast(u32, r);
#endif
}

// ---------------- prep: weights -> f16 fragment order / pair layouts --------
__global__ __launch_bounds__(256) void prep3(
    const float* __restrict__ sw, const float* __restrict__ e1w,
    const float* __restrict__ e2w, const float* __restrict__ fw,
    const float* __restrict__ gw, const float* __restrict__ rw,
    f16* __restrict__ wsk, f16* __restrict__ e1f, f16* __restrict__ e2f,
    u32* __restrict__ fgp, u32* __restrict__ ggp, u32* __restrict__ rwp){
  int idx = blockIdx.x*256 + threadIdx.x;
  if (idx < 30720){                    // skip weights frag: [i][mt][lane][8]
    int lane = idx & 63, mt = (idx>>6)&15, i = idx>>10;
    int m = mt*16 + (lane&15);
    int kl = (lane>>4)*8;
    const float* s = sw + ((size_t)i*SKC + m)*NC + kl;
    f16* dp = wsk + (size_t)idx*8;
    #pragma unroll
    for (int j=0;j<8;j++) dp[j] = (f16)s[j];
  } else if (idx < 38912){             // e1 frag: [ks][mt][lane][8]
    int j2 = idx - 30720;
    int lane = j2&63, mt = (j2>>6)&15, ks = j2>>10;
    int m = mt*16 + (lane&15);
    int k = ks*32 + (lane>>4)*8;
    const float* s = e1w + (size_t)m*SKC + k;
    f16* dp = e1f + (size_t)j2*8;
    #pragma unroll
    for (int j=0;j<8;j++) dp[j] = (f16)s[j];
  } else if (idx < 47104){             // e2 frag
    int j2 = idx - 38912;
    int lane = j2&63, mt = (j2>>6)&15, ks = j2>>10;
    int m = mt*16 + (lane&15);
    int k = ks*32 + (lane>>4)*8;
    const float* s = e2w + (size_t)m*SKC + k;
    f16* dp = e2f + (size_t)j2*8;
    #pragma unroll
    for (int j=0;j<8;j++) dp[j] = (f16)s[j];
  } else if (idx < 77824){             // filt pairs, exp2-scaled
    int j2 = idx - 47104;
    const float* s = fw + (size_t)j2*2;
    f16x2 p; p.x = (f16)(s[0]*SCF); p.y = (f16)(s[1]*SCF);
    fgp[j2] = __builtin_bit_cast(u32, p);
  } else if (idx < 108544){            // gate pairs, exp2-scaled
    int j2 = idx - 77824;
    const float* s = gw + (size_t)j2*2;
    f16x2 p; p.x = (f16)(s[0]*SCG); p.y = (f16)(s[1]*SCG);
    ggp[j2] = __builtin_bit_cast(u32, p);
  } else if (idx < 123904){            // res rows
    int j2 = idx - 108544;
    int i = j2 >> 9, c = (j2>>4)&31, j = j2&15;
    const float* s = rw + ((size_t)i*NC + c)*NC + 2*j;
    f16x2 p; p.x = (f16)s[0]; p.y = (f16)s[1];
    rwp[j2] = __builtin_bit_cast(u32, p);
  }
}

// ---------------- per-layer weight fragments ----------------
struct LW { f16x8 af[4]; f16x8 ag[4]; f16x8 ar[2]; };
__device__ __forceinline__ void lw_load(LW& w, const u32* __restrict__ fp,
    const u32* __restrict__ gp, const u32* __restrict__ rp, int lane){
  int m = lane & 15, q4 = (lane >> 4) * 4;
  #pragma unroll
  for (int mh = 0; mh < 2; mh++){
    #pragma unroll
    for (int kc = 0; kc < 2; kc++){
      w.af[mh*2+kc] = *(const f16x8*)&fp[(mh*16+m)*32 + kc*16 + q4];
      w.ag[mh*2+kc] = *(const f16x8*)&gp[(mh*16+m)*32 + kc*16 + q4];
    }
    w.ar[mh] = *(const f16x8*)&rp[(mh*16+m)*16 + q4];
  }
}

// ---------------- 16-col tile engine: conv->gate->res via MFMA --------------
__device__ __forceinline__ void tile_core(const LW& w,
    uint2 a0, uint2 a1, uint2 b0, uint2 b1,
    u32* zbw, int lane, uint2& xo0, uint2& xo1){
  uint4 B0u = make_uint4(perm_lo(a0.x,b0.x), perm_hi(a0.x,b0.x),
                         perm_lo(a0.y,b0.y), perm_hi(a0.y,b0.y));
  uint4 B1u = make_uint4(perm_lo(a1.x,b1.x), perm_hi(a1.x,b1.x),
                         perm_lo(a1.y,b1.y), perm_hi(a1.y,b1.y));
  f16x8 B0 = __builtin_bit_cast(f16x8, B0u);
  f16x8 B1 = __builtin_bit_cast(f16x8, B1u);
  f32x4 z4 = {0.f,0.f,0.f,0.f};
  f32x4 fa0 = MFMA16(w.af[0], B0, z4); fa0 = MFMA16(w.af[1], B1, fa0);
  f32x4 fa1 = MFMA16(w.af[2], B0, z4); fa1 = MFMA16(w.af[3], B1, fa1);
  f32x4 ga0 = MFMA16(w.ag[0], B0, z4); ga0 = MFMA16(w.ag[1], B1, ga0);
  f32x4 ga1 = MFMA16(w.ag[2], B0, z4); ga1 = MFMA16(w.ag[3], B1, ga1);
  u32 zq[4];
  #pragma unroll
  for (int mh = 0; mh < 2; mh++){
    f32x4 fv = mh ? fa1 : fa0;
    f32x4 gv = mh ? ga1 : ga0;
    float zz[4];
    #pragma unroll
    for (int r = 0; r < 4; r++){
      float fc = fminf(fmaxf(fv[r], -CLF), CLF);
      float gc = fminf(fmaxf(gv[r], -CLG), CLG);
      float ef = fexp2(fc);
      float eg = fexp2(gc);
      zz[r] = (1.f - ef) * frcp((1.f + ef) * (1.f + eg));
    }
    zq[mh*2+0] = pk2(zz[0], zz[1]);
    zq[mh*2+1] = pk2(zz[2], zz[3]);
  }
  int t = lane & 15, q = lane >> 4;
  *(uint2*)&zbw[t*ZBS + q*2]     = make_uint2(zq[0], zq[1]);
  *(uint2*)&zbw[t*ZBS + 8 + q*2] = make_uint2(zq[2], zq[3]);
  f16x8 zB = *(const f16x8*)&zbw[t*ZBS + q*4];
  f32x4 r0 = MFMA16(w.ar[0], zB, z4);
  f32x4 r1 = MFMA16(w.ar[1], zB, z4);
  f16x2 b00 = __builtin_bit_cast(f16x2, b0.x);
  f16x2 b01 = __builtin_bit_cast(f16x2, b0.y);
  f16x2 b10 = __builtin_bit_cast(f16x2, b1.x);
  f16x2 b11 = __builtin_bit_cast(f16x2, b1.y);
  xo0.x = pk2(r0[0] + (float)b00.x, r0[1] + (float)b00.y);
  xo0.y = pk2(r0[2] + (float)b01.x, r0[3] + (float)b01.y);
  xo1.x = pk2(r1[0] + (float)b10.x, r1[1] + (float)b10.y);
  xo1.y = pk2(r1[2] + (float)b11.x, r1[3] + (float)b11.y);
}

// ---------------- fused 7-layer group (d=1..64), MFMA, 192-col blocks -------
struct Trim7 { int t[7]; };

__global__ __launch_bounds__(256, 2) void group7m(
    const f16* __restrict__ xin, const float* __restrict__ y,
    const float* __restrict__ cw, const float* __restrict__ cb, int tc0,
    f16* __restrict__ xout, f16* __restrict__ zbase, int g0,
    int Lfinal, int TcAct,
    const u32* __restrict__ fgp, const u32* __restrict__ ggp,
    const u32* __restrict__ rwp, Trim7 trims){
  __shared__ u32 xb[2][XBC*XBS];    // 61,440 B
  __shared__ u32 zbuf[4][16*ZBS];   //  5,120 B
  int tid = threadIdx.x, b = blockIdx.y, o0 = blockIdx.x*WGRP;
  int lane = tid & 63, widx = tid >> 6;
  int Cf = Lfinal - o0; if (Cf > WGRP) Cf = WGRP;
  int Cin = Cf + 127;
  for (int p = tid; p < Cin; p += 256){
    u32* dst = &xb[0][p*XBS];
    if (y != nullptr){
      float yv = y[(size_t)b*T0 + tc0 + o0 + p];
      #pragma unroll
      for (int j = 0; j < 16; j++)
        dst[j] = pk2(fmaf(cw[2*j], yv, cb[2*j]), fmaf(cw[2*j+1], yv, cb[2*j+1]));
    } else {
      const uint4* src = (const uint4*)(xin + ((size_t)b*XPB + o0 + p)*NC);
      uint4* d4 = (uint4*)dst;
      d4[0]=src[0]; d4[1]=src[1]; d4[2]=src[2]; d4[3]=src[3];
    }
  }
  __syncthreads();
  int cur = 0;
  #pragma unroll 1
  for (int li = 0; li < 7; li++){
    int d = 1 << li;
    int count = Cf + 128 - (2 << li);
    LW w;
    lw_load(w, fgp + (size_t)(g0+li)*1024, ggp + (size_t)(g0+li)*1024,
            rwp + (size_t)(g0+li)*512, lane);
    f16* zl = zbase + (size_t)(g0+li)*ZLS + (size_t)b*TC*NC;
    int trim = trims.t[li];
    int ntiles = (count + 15) >> 4;
    u32* zbw = zbuf[widx];
    for (int ti = widx; ti < ntiles; ti += 4){
      int t0 = ti*16;
      int c = t0 + (lane & 15), q = lane >> 4;
      const u32* xc = &xb[cur][c*XBS];
      const u32* xd = &xb[cur][(c+d)*XBS];
      uint2 a0 = *(const uint2*)&xc[q*2];
      uint2 a1 = *(const uint2*)&xc[8 + q*2];
      uint2 b0 = *(const uint2*)&xd[q*2];
      uint2 b1 = *(const uint2*)&xd[8 + q*2];
      uint2 xo0, xo1;
      tile_core(w, a0, a1, b0, b1, zbw, lane, xo0, xo1);
      u32* xn = &xb[cur^1][c*XBS];
      *(uint2*)&xn[q*2] = xo0;
      *(uint2*)&xn[8 + q*2] = xo1;
      int zr = lane >> 2, zc4 = (lane & 3) * 4;
      uint4 zv = *(const uint4*)&zbw[zr*ZBS + zc4];
      int p = t0 + zr;
      int lz = o0 + p - trim;
      if (p < count && lz >= 0 && lz < TcAct)
        *(uint4*)(zl + (size_t)lz*NC + zc4*2) = zv;
    }
    __syncthreads();
    cur ^= 1;
  }
  for (int p = tid; p < Cf; p += 256){
    const uint4* s = (const uint4*)&xb[cur][p*XBS];
    uint4* dd = (uint4*)(xout + ((size_t)b*XPB + o0 + p)*NC);
    dd[0]=s[0]; dd[1]=s[1]; dd[2]=s[2]; dd[3]=s[3];
  }
}

// ---------------- single dilated layer (d=128/256/512), MFMA, global --------
__global__ __launch_bounds__(256, 4) void singlem(
    const f16* __restrict__ xin, f16* __restrict__ xout, f16* __restrict__ zl,
    const u32* __restrict__ fp, const u32* __restrict__ gp,
    const u32* __restrict__ rp, int Tout, int d, int trim, int TcAct){
  __shared__ u32 zbuf[4][16*ZBS];
  int tid = threadIdx.x, b = blockIdx.y;
  int lane = tid & 63, widx = tid >> 6;
  int t0 = (blockIdx.x*4 + widx) * 16;
  if (t0 >= Tout) return;
  LW w;
  lw_load(w, fp, gp, rp, lane);
  int c = t0 + (lane & 15), q = lane >> 4;
  const f16* xc = xin + ((size_t)b*XPB + c)*NC;
  const f16* xd = xc + (size_t)d*NC;
  uint2 a0 = *(const uint2*)(xc + q*4);
  uint2 a1 = *(const uint2*)(xc + 16 + q*4);
  uint2 b0 = *(const uint2*)(xd + q*4);
  uint2 b1 = *(const uint2*)(xd + 16 + q*4);
  uint2 xo0, xo1;
  tile_core(w, a0, a1, b0, b1, zbuf[widx], lane, xo0, xo1);
  if (c < Tout){
    f16* xoc = xout + ((size_t)b*XPB + c)*NC;
    *(uint2*)(xoc + q*4) = xo0;
    *(uint2*)(xoc + 16 + q*4) = xo1;
  }
  int zr = lane >> 2, zc4 = (lane & 3) * 4;
  uint4 zv = *(const uint4*)&zbuf[widx][zr*ZBS + zc4];
  int p = t0 + zr, lz = p - trim;
  if (p < Tout && lz >= 0 && lz < TcAct)
    *(uint4*)(zl + ((size_t)b*TC + lz)*NC + zc4*2) = zv;
}

// ------- fused skip(K=960) -> relu -> end1 -> relu -> end2, write f32 -------
// M-split: wave w owns mt = w*4..w*4+3 for all 64 t. A-frags direct from L2,
// pipelined one layer ahead; z double-buffered in LDS (80B stride, conflict-
// free); sA/sB/zlds all alias one 33.8KB buffer -> 3 blocks/CU.
__global__ __launch_bounds__(256, 3) void skipend(
    const f16* __restrict__ zbase,
    const f16* __restrict__ wsk, const f16* __restrict__ e1f,
    const float* __restrict__ e1b, const f16* __restrict__ e2f,
    const float* __restrict__ e2b, float* __restrict__ out,
    int tc0, int TcAct){
  __shared__ u32 smem[64*132];        // 33,792 B (sA/sB); zlds aliases front
  u32* zlds0 = smem;                  // [64][20] u32
  u32* zlds1 = smem + 64*20;
  int tid = threadIdx.x, b = blockIdx.y, t0 = blockIdx.x*64;
  int w = tid>>6, lane = tid&63;
  int tl = lane & 15;
  int q  = lane >> 4;
  const uint4* wsk4 = (const uint4*)wsk;
  const uint4* e1f4 = (const uint4*)e1f;
  const uint4* e2f4 = (const uint4*)e2f;

  const f16* zcol = zbase + ((size_t)b*TC + t0 + (tid>>2))*NC + (tid&3)*8;
  int zw = (tid>>2)*20 + (tid&3)*4;

  f32x4 acc[4][4];
  #pragma unroll
  for (int j=0;j<4;j++)
    #pragma unroll
    for (int tt=0;tt<4;tt++) acc[j][tt] = f32x4{0.f,0.f,0.f,0.f};

  uint4 awA[4], awB[4], zst;
  // prologue: layer 0
  zst = *(const uint4*)zcol;
  #pragma unroll
  for (int j=0;j<4;j++) awA[j] = wsk4[(size_t)(w*4+j)*64 + lane];
  *(uint4*)&zlds0[zw] = zst;

  #pragma unroll 1
  for (int l = 0; l < NL; l += 2){
    __syncthreads();
    // prefetch layer l+1 (always exists: l <= 28)
    zst = *(const uint4*)(zcol + (size_t)(l+1)*ZLS);
    #pragma unroll
    for (int j=0;j<4;j++)
      awB[j] = wsk4[(size_t)(l+1)*1024 + (w*4+j)*64 + lane];
    {
      f16x8 zb[4];
      #pragma unroll
      for (int tt=0;tt<4;tt++)
        zb[tt] = *(const f16x8*)&zlds0[(tt*16+tl)*20 + q*4];
      #pragma unroll
      for (int j=0;j<4;j++){
        f16x8 a = __builtin_bit_cast(f16x8, awA[j]);
        #pragma unroll
        for (int tt=0;tt<4;tt++)
          acc[j][tt] = MFMA16(a, zb[tt], acc[j][tt]);
      }
    }
    *(uint4*)&zlds1[zw] = zst;
    __syncthreads();
    if (l+2 < NL){
      zst = *(const uint4*)(zcol + (size_t)(l+2)*ZLS);
      #pragma unroll
      for (int j=0;j<4;j++)
        awA[j] = wsk4[(size_t)(l+2)*1024 + (w*4+j)*64 + lane];
    }
    {
      f16x8 zb[4];
      #pragma unroll
      for (int tt=0;tt<4;tt++)
        zb[tt] = *(const f16x8*)&zlds1[(tt*16+tl)*20 + q*4];
      #pragma unroll
      for (int j=0;j<4;j++){
        f16x8 a = __builtin_bit_cast(f16x8, awB[j]);
        #pragma unroll
        for (int tt=0;tt<4;tt++)
          acc[j][tt] = MFMA16(a, zb[tt], acc[j][tt]);
      }
    }
    if (l+2 < NL) *(uint4*)&zlds0[zw] = zst;
  }
  __syncthreads();
  // phase2: relu(skip) -> sA [t][264 f16]
  int rq = q*4;
  #pragma unroll
  for (int j=0;j<4;j++){
    int c0 = (w*4+j)*16 + rq;
    #pragma unroll
    for (int tt=0;tt<4;tt++){
      int t = tt*16 + tl;
      u32 p0 = pk2(fmaxf(acc[j][tt][0],0.f), fmaxf(acc[j][tt][1],0.f));
      u32 p1 = pk2(fmaxf(acc[j][tt][2],0.f), fmaxf(acc[j][tt][3],0.f));
      *(uint2*)&smem[t*132 + (c0>>1)] = make_uint2(p0, p1);
    }
  }
  __syncthreads();
  // phase3: end1
  #pragma unroll
  for (int j=0;j<4;j++)
    #pragma unroll
    for (int tt=0;tt<4;tt++) acc[j][tt] = f32x4{0.f,0.f,0.f,0.f};
  #pragma unroll
  for (int ks=0;ks<8;ks++){
    f16x8 zb[4];
    #pragma unroll
    for (int tt=0;tt<4;tt++)
      zb[tt] = *(const f16x8*)&smem[(tt*16+tl)*132 + ks*16 + q*4];
    #pragma unroll
    for (int j=0;j<4;j++){
      f16x8 a = __builtin_bit_cast(f16x8, e1f4[(size_t)(ks*16 + w*4+j)*64 + lane]);
      #pragma unroll
      for (int tt=0;tt<4;tt++)
        acc[j][tt] = MFMA16(a, zb[tt], acc[j][tt]);
    }
  }
  __syncthreads();     // all sA reads done; safe to overwrite with sB
  #pragma unroll
  for (int j=0;j<4;j++){
    int c0 = (w*4+j)*16 + rq;
    float4 bv = *(const float4*)&e1b[c0];
    #pragma unroll
    for (int tt=0;tt<4;tt++){
      int t = tt*16 + tl;
      u32 p0 = pk2(fmaxf(acc[j][tt][0]+bv.x,0.f), fmaxf(acc[j][tt][1]+bv.y,0.f));
      u32 p1 = pk2(fmaxf(acc[j][tt][2]+bv.z,0.f), fmaxf(acc[j][tt][3]+bv.w,0.f));
      *(uint2*)&smem[t*132 + (c0>>1)] = make_uint2(p0, p1);
    }
  }
  __syncthreads();
  // phase4: end2 + final write
  #pragma unroll
  for (int j=0;j<4;j++)
    #pragma unroll
    for (int tt=0;tt<4;tt++) acc[j][tt] = f32x4{0.f,0.f,0.f,0.f};
  #pragma unroll
  for (int ks=0;ks<8;ks++){
    f16x8 zb[4];
    #pragma unroll
    for (int tt=0;tt<4;tt++)
      zb[tt] = *(const f16x8*)&smem[(tt*16+tl)*132 + ks*16 + q*4];
    #pragma unroll
    for (int j=0;j<4;j++){
      f16x8 a = __builtin_bit_cast(f16x8, e2f4[(size_t)(ks*16 + w*4+j)*64 + lane]);
      #pragma unroll
      for (int tt=0;tt<4;tt++)
        acc[j][tt] = MFMA16(a, zb[tt], acc[j][tt]);
    }
  }
  #pragma unroll
  for (int j=0;j<4;j++){
    int c0 = (w*4+j)*16 + rq;
    float4 bv = *(const float4*)&e2b[c0];
    #pragma unroll
    for (int tt=0;tt<4;tt++){
      int t = tt*16 + tl;
      if (t0 + t < TcAct){
        float* op = out + ((size_t)b*SKC + c0)*TF + tc0 + t0 + t;
        op[0*TF] = acc[j][tt][0] + bv.x;
        op[1*TF] = acc[j][tt][1] + bv.y;
        op[2*TF] = acc[j][tt][2] + bv.z;
        op[3*TF] = acc[j][tt][3] + bv.w;
      }
    }
  }
}

extern "C" void kernel_launch(void* const* d_in, const int* in_sizes, int n_in,
                              void* d_out, int out_size, void* d_ws, size_t ws_size,
                              hipStream_t stream) {
  (void)in_sizes; (void)n_in; (void)out_size; (void)ws_size;
  const float* y   = (const float*)d_in[0];
  const float* cw  = (const float*)d_in[1];
  const float* cb  = (const float*)d_in[2];
  const float* fw  = (const float*)d_in[3];
  const float* gw  = (const float*)d_in[4];
  const float* rw  = (const float*)d_in[5];
  const float* sw  = (const float*)d_in[6];
  const float* e1w = (const float*)d_in[7];
  const float* e1b = (const float*)d_in[8];
  const float* e2w = (const float*)d_in[9];
  const float* e2b = (const float*)d_in[10];
  float* out = (float*)d_out;
  char* ws = (char*)d_ws;

  // ws layout, total 86,781,952 B (proven ws >= 89,403,392)
  f16* wsk  = (f16*)(ws);                       //   491,520
  f16* e1f  = (f16*)(ws +   491520);            //   131,072
  f16* e2f  = (f16*)(ws +   622592);            //   131,072
  u32* fgp  = (u32*)(ws +  753664);             //   122,880
  u32* ggp  = (u32*)(ws +  876544);             //   122,880
  u32* rwp  = (u32*)(ws +  999424);             //    61,440
  f16* xpA  = (f16*)(ws + 1060864);             // 5,505,024
  f16* xpB  = (f16*)(ws + 6565888);             // 5,505,024
  f16* zstack = (f16*)(ws + 12070912);          // 74,711,040

  int S[NL+1]; S[NL] = 0;
  for (int i = NL-1; i >= 0; i--) S[i] = S[i+1] + (1 << (i % 10));

  prep3<<<dim3(484), 256, 0, stream>>>(sw, e1w, e2w, fw, gw, rw,
                                       wsk, e1f, e2f, fgp, ggp, rwp);

  f16* bufs[2] = {xpA, xpB};
  for (int tc0 = 0; tc0 < TF; tc0 += TC){
    int TcAct = TF - tc0; if (TcAct > TC) TcAct = TC;
    int cur = 0;
    for (int s = 0; s < 3; s++){
      int g0 = s*10;
      Trim7 tr;
      for (int li = 0; li < 7; li++) tr.t[li] = S[g0+li+1];
      int Lfinal = TcAct + S[g0+7];
      const f16* gin = (s == 0) ? (const f16*)nullptr : bufs[cur];
      const float* yArg = (s == 0) ? y : (const float*)nullptr;
      int nxt = (s == 0) ? 0 : (cur ^ 1);
      group7m<<<dim3((Lfinal + WGRP-1)/WGRP, NB), 256, 0, stream>>>(
          gin, yArg, cw, cb, tc0, bufs[nxt], zstack, g0, Lfinal, TcAct,
          fgp, ggp, rwp, tr);
      cur = nxt;
      for (int i = g0+7; i <= g0+9; i++){
        int d = 1 << (i % 10);
        int Tout = TcAct + S[i+1];
        singlem<<<dim3((Tout + 63)/64, NB), 256, 0, stream>>>(
            bufs[cur], bufs[cur^1], zstack + (size_t)i*ZLS,
            fgp + (size_t)i*1024, ggp + (size_t)i*1024, rwp + (size_t)i*512,
            Tout, d, S[i+1], TcAct);
        cur ^= 1;
      }
    }
    skipend<<<dim3((TcAct + 63)/64, NB), 256, 0, stream>>>(
        zstack, wsk, e1f, e1b, e2f, e2b, out, tc0, TcAct);
  }
}